// Round 7
// baseline (246.395 us; speedup 1.0000x reference)
//
#include <hip/hip_runtime.h>
#include <hip/hip_bf16.h>

typedef __hip_bfloat16 bf16_t;
typedef __attribute__((ext_vector_type(8))) short  s16x8;   // 8 bf16 MFMA operand
typedef __attribute__((ext_vector_type(4))) float  f32x4;   // MFMA accumulator

#define N_ROWS 8192
#define D_DIM  1024

// async global->LDS, 16B/lane; LDS dest = wave-uniform base + lane*16B
#define GLOAD_LDS16(g, l)                                                     \
  __builtin_amdgcn_global_load_lds(                                           \
      (const __attribute__((address_space(1))) void*)(g),                     \
      (__attribute__((address_space(3))) void*)(l), 16, 0, 0)

#define WAITCNT_VM(n) asm volatile("s_waitcnt vmcnt(" #n ")" ::: "memory")

struct alignas(8) bf16x4_s { bf16_t x, y, z, w; };

// ---------------------------------------------------------------------------
// Kernel 1: per-row L2 normalize (fp32 in) -> bf16 out. One WAVE per row,
// barrier-free (butterfly shfl). Block = 4 waves = 4 rows.
// Blocks 0..31 also zero the 8192-entry rowsum accumulator (replaces memset).
// ---------------------------------------------------------------------------
__global__ void __launch_bounds__(256) normalize_kernel(
    const float* __restrict__ z, bf16_t* __restrict__ out,
    float* __restrict__ rowsum) {
  const int t = threadIdx.x;
  if (blockIdx.x < 32) rowsum[blockIdx.x * 256 + t] = 0.f;
  const int row  = blockIdx.x * 4 + (t >> 6);
  const int lane = t & 63;
  const float4* rp = (const float4*)(z + (size_t)row * D_DIM);
  float4 v[4];
#pragma unroll
  for (int j = 0; j < 4; ++j) v[j] = rp[lane + 64 * j];
  float ss = 0.f;
#pragma unroll
  for (int j = 0; j < 4; ++j)
    ss += v[j].x * v[j].x + v[j].y * v[j].y + v[j].z * v[j].z + v[j].w * v[j].w;
  ss += __shfl_xor(ss, 1);
  ss += __shfl_xor(ss, 2);
  ss += __shfl_xor(ss, 4);
  ss += __shfl_xor(ss, 8);
  ss += __shfl_xor(ss, 16);
  ss += __shfl_xor(ss, 32);
  const float rn = rsqrtf(ss);
  bf16x4_s* op = (bf16x4_s*)(out + (size_t)row * D_DIM);
#pragma unroll
  for (int j = 0; j < 4; ++j) {
    bf16x4_s o;
    o.x = __float2bfloat16(v[j].x * rn);
    o.y = __float2bfloat16(v[j].y * rn);
    o.z = __float2bfloat16(v[j].z * rn);
    o.w = __float2bfloat16(v[j].w * rn);
    op[lane + 64 * j] = o;
  }
}

// ---------------------------------------------------------------------------
// Kernel 2: 256x256-tile NT-GEMM (m = A.B^T) + exp + row-sum + diag capture.
// 512 threads = 8 waves (2 row-waves x 4 col-waves); wave output = 128x64.
// BK=32, ring-4 LDS buffers (128 KiB): compute kt from buf[kt%4] while
// staging kt+3 into buf[(kt+3)%4]; boundary s_waitcnt vmcnt(8) (counted,
// 2 tiles stay in flight) + raw s_barrier. Prefetch distance ~2 iters.
// LDS swizzle: 16B-chunk c' = c ^ ((row>>1)&3), applied on the global
// source during staging (gload_lds writes linearly) and on ds_read addrs.
// ---------------------------------------------------------------------------
__global__ void __launch_bounds__(512, 2) simexp_gemm(
    const bf16_t* __restrict__ A, const bf16_t* __restrict__ B,
    float* __restrict__ rowsum, float* __restrict__ pos_sim) {
  constexpr int BK   = 32;
  constexpr int ABUF = 256 * BK;      // 8192 elems (16 KiB) per A (or B) slab
  constexpr int BUFE = 2 * ABUF;      // one ring slot: A slab + B slab
  __shared__ bf16_t lds[4 * BUFE];    // 128 KiB

  const int t    = threadIdx.x;
  const int w    = t >> 6;            // 0..7
  const int lane = t & 63;
  const int wr   = w >> 2;            // 0..1  -> rows wr*128..+128
  const int wc   = w & 3;             // 0..3  -> cols wc*64..+64
  const int rb   = blockIdx.y, cb = blockIdx.x;
  const int row0 = rb * 256, col0 = cb * 256;

  // --- staging source addressing (pre-swizzled global source, rule 21) ---
  // stage instr i covers LDS linear elems [i*4096 + t*8); row = i*128+(t>>2),
  // phys chunk = t&3; it must hold logical chunk (t&3)^((row>>1)&3).
  const int srow = t >> 2;                                  // 0..127
  const int scol = (((t & 3) ^ ((t >> 3) & 3))) * 8;        // swizzled 16B chunk
  const size_t gA0 = (size_t)(row0 + srow) * D_DIM + scol;
  const size_t gA1 = gA0 + (size_t)128 * D_DIM;
  const size_t gB0 = (size_t)(col0 + srow) * D_DIM + scol;
  const size_t gB1 = gB0 + (size_t)128 * D_DIM;
  const int ldst = w * 512;           // wave-uniform dest base (elems) per instr

#define STAGE_A(dst, k0)                                        \
  do {                                                          \
    GLOAD_LDS16(A + gA0 + (k0), (dst) + ldst);                  \
    GLOAD_LDS16(A + gA1 + (k0), (dst) + 4096 + ldst);           \
  } while (0)
#define STAGE_B(dst, k0)                                        \
  do {                                                          \
    GLOAD_LDS16(B + gB0 + (k0), (dst) + ABUF + ldst);           \
    GLOAD_LDS16(B + gB1 + (k0), (dst) + ABUF + 4096 + ldst);    \
  } while (0)

  // --- fragment read offsets (swizzled, element units) ---
  int offA[8], offB[4];
#pragma unroll
  for (int m = 0; m < 8; ++m) {
    const int r = wr * 128 + m * 16 + (lane & 15);
    offA[m] = r * 32 + (((lane >> 4) ^ ((r >> 1) & 3)) * 8);
  }
#pragma unroll
  for (int n = 0; n < 4; ++n) {
    const int r = wc * 64 + n * 16 + (lane & 15);
    offB[n] = r * 32 + (((lane >> 4) ^ ((r >> 1) & 3)) * 8);
  }

  f32x4 acc[8][4];
#pragma unroll
  for (int m = 0; m < 8; ++m)
#pragma unroll
    for (int n = 0; n < 4; ++n) acc[m][n] = (f32x4){0.f, 0.f, 0.f, 0.f};

  // prologue: tiles 0,1,2 -> slots 0,1,2 (12 loads); drain tile 0 (keep 8)
  STAGE_A(lds, 0);                 STAGE_B(lds, 0);
  STAGE_A(lds + BUFE, BK);         STAGE_B(lds + BUFE, BK);
  STAGE_A(lds + 2 * BUFE, 2 * BK); STAGE_B(lds + 2 * BUFE, 2 * BK);
  WAITCNT_VM(8);
  __builtin_amdgcn_s_barrier();

#pragma unroll 1
  for (int kt = 0; kt < 32; ++kt) {
    const int k0n = (kt + 3) * BK;
    const bf16_t* Ab = lds + (kt & 3) * BUFE;
    const bf16_t* Bb = Ab + ABUF;
    bf16_t* nxt = lds + ((kt + 3) & 3) * BUFE;

    // ---- phase 1: issue A-stage (kt+3), read B + A(lo), 16 MFMA ----
    if (kt < 29) STAGE_A(nxt, k0n);
    s16x8 bf[4];
#pragma unroll
    for (int n = 0; n < 4; ++n) bf[n] = *(const s16x8*)&Bb[offB[n]];
    s16x8 af[4];
#pragma unroll
    for (int m = 0; m < 4; ++m) af[m] = *(const s16x8*)&Ab[offA[m]];
    __builtin_amdgcn_s_setprio(1);
#pragma unroll
    for (int m = 0; m < 4; ++m)
#pragma unroll
      for (int n = 0; n < 4; ++n)
        acc[m][n] = __builtin_amdgcn_mfma_f32_16x16x32_bf16(
            af[m], bf[n], acc[m][n], 0, 0, 0);
    __builtin_amdgcn_s_setprio(0);

    // ---- phase 2: issue B-stage (kt+3), read A(hi), 16 MFMA ----
    if (kt < 29) STAGE_B(nxt, k0n);
#pragma unroll
    for (int m = 0; m < 4; ++m) af[m] = *(const s16x8*)&Ab[offA[m + 4]];
    __builtin_amdgcn_s_setprio(1);
#pragma unroll
    for (int m = 0; m < 4; ++m)
#pragma unroll
      for (int n = 0; n < 4; ++n)
        acc[m + 4][n] = __builtin_amdgcn_mfma_f32_16x16x32_bf16(
            af[m], bf[n], acc[m + 4][n], 0, 0, 0);
    __builtin_amdgcn_s_setprio(0);

    // ---- boundary: ensure tile kt+1 landed; keep kt+2/kt+3 in flight ----
    if (kt < 29) {
      WAITCNT_VM(8);
      __builtin_amdgcn_s_barrier();
    } else if (kt == 29) {
      WAITCNT_VM(4);
      __builtin_amdgcn_s_barrier();
    } else if (kt == 30) {
      WAITCNT_VM(0);
      __builtin_amdgcn_s_barrier();
    }
  }

  // ---- epilogue ----
  // diagonal capture (independent of the LDS reduction below)
  if (rb == cb) {
#pragma unroll
    for (int m = 0; m < 8; ++m)
#pragma unroll
      for (int n = 0; n < 4; ++n)
#pragma unroll
        for (int r = 0; r < 4; ++r) {
          const int grow = wr * 128 + m * 16 + (lane >> 4) * 4 + r;
          const int gcol = wc * 64 + n * 16 + (lane & 15);
          if (grow == gcol) pos_sim[row0 + grow] = acc[m][n][r];
        }
  }

  __syncthreads();                       // all LDS K-tile reads done; reuse lds
  float* red = (float*)lds;              // [4 wc][256 rows]
#pragma unroll
  for (int m = 0; m < 8; ++m)
#pragma unroll
    for (int r = 0; r < 4; ++r) {
      float s = 0.f;
#pragma unroll
      for (int n = 0; n < 4; ++n) s += __expf(acc[m][n][r]);
      s += __shfl_xor(s, 1);
      s += __shfl_xor(s, 2);
      s += __shfl_xor(s, 4);
      s += __shfl_xor(s, 8);
      if ((lane & 15) == 0) {
        const int row_local = wr * 128 + m * 16 + (lane >> 4) * 4 + r;
        red[wc * 256 + row_local] = s;
      }
    }
  __syncthreads();
  if (t < 256) {
    const float s4 = red[t] + red[256 + t] + red[512 + t] + red[768 + t];
    atomicAdd(&rowsum[row0 + t], s4);
  }
#undef STAGE_A
#undef STAGE_B
}

// ---------------------------------------------------------------------------
// Kernel 3: finalize — p_ij, loss, means. Single block.
// ---------------------------------------------------------------------------
__global__ void __launch_bounds__(256) finalize_kernel(
    const float* __restrict__ rowsum, const float* __restrict__ pos_sim,
    float* __restrict__ out) {
  const int t = threadIdx.x;
  double lsum = 0.0, psum = 0.0;
  for (int i = t; i < N_ROWS; i += 256) {
    const float ps    = pos_sim[i];
    const float pos   = expf(ps);
    const float denom = rowsum[i] - pos;
    const float p     = pos / denom;
    lsum += (double)(-logf(p) - p * ps);
    psum += (double)p;
  }
  for (int off = 32; off; off >>= 1) {
    lsum += __shfl_down(lsum, off);
    psum += __shfl_down(psum, off);
  }
  __shared__ double sl[4], sp[4];
  const int wv = t >> 6, ln = t & 63;
  if (ln == 0) { sl[wv] = lsum; sp[wv] = psum; }
  __syncthreads();
  if (t == 0) {
    const double L = sl[0] + sl[1] + sl[2] + sl[3];
    const double P = sp[0] + sp[1] + sp[2] + sp[3];
    out[0] = (float)(L / N_ROWS);
    out[1] = (float)(P / N_ROWS);
  }
}

// ---------------------------------------------------------------------------
extern "C" void kernel_launch(void* const* d_in, const int* in_sizes, int n_in,
                              void* d_out, int out_size, void* d_ws,
                              size_t ws_size, hipStream_t stream) {
  const float* z = (const float*)d_in[0];
  float* out = (float*)d_out;

  char* ws = (char*)d_ws;
  bf16_t* AB = (bf16_t*)ws;  // normalized bf16, 2*N*D = 32 MiB
  float* rowsum  = (float*)(ws + (size_t)2 * N_ROWS * D_DIM * sizeof(bf16_t));
  float* pos_sim = rowsum + N_ROWS;

  normalize_kernel<<<2 * N_ROWS / 4, 256, 0, stream>>>(z, AB, rowsum);

  bf16_t* Amat = AB;
  bf16_t* Bmat = AB + (size_t)N_ROWS * D_DIM;
  dim3 grid(N_ROWS / 256, N_ROWS / 256);  // (cb, rb) = 32 x 32
  simexp_gemm<<<grid, 512, 0, stream>>>(Amat, Bmat, rowsum, pos_sim);

  finalize_kernel<<<1, 256, 0, stream>>>(rowsum, pos_sim, out);
}

// Round 10
// 229.995 us; speedup vs baseline: 1.0713x; 1.0713x over previous
//
#include <hip/hip_runtime.h>
#include <hip/hip_bf16.h>

typedef __hip_bfloat16 bf16_t;
typedef __attribute__((ext_vector_type(8))) short  s16x8;   // 8 bf16 MFMA operand
typedef __attribute__((ext_vector_type(4))) float  f32x4;   // MFMA accumulator

#define N_ROWS 8192
#define D_DIM  1024

// async global->LDS, 16B/lane; LDS dest = wave-uniform base + lane*16B
#define GLOAD_LDS16(g, l)                                                     \
  __builtin_amdgcn_global_load_lds(                                           \
      (const __attribute__((address_space(1))) void*)(g),                     \
      (__attribute__((address_space(3))) void*)(l), 16, 0, 0)

#define WAITCNT_VM(n) asm volatile("s_waitcnt vmcnt(" #n ")" ::: "memory")
#define BARRIER_()                                                            \
  do {                                                                        \
    asm volatile("" ::: "memory");                                            \
    __builtin_amdgcn_s_barrier();                                             \
    asm volatile("" ::: "memory");                                            \
  } while (0)

struct alignas(8) bf16x4_s { bf16_t x, y, z, w; };

// ---------------------------------------------------------------------------
// Kernel 1: per-row L2 normalize (fp32 in) -> bf16 out. One WAVE per row,
// barrier-free (butterfly shfl). Block = 4 waves = 4 rows.
// Blocks 0..31 also zero the 8192-entry rowsum accumulator (replaces memset).
// ---------------------------------------------------------------------------
__global__ void __launch_bounds__(256) normalize_kernel(
    const float* __restrict__ z, bf16_t* __restrict__ out,
    float* __restrict__ rowsum) {
  const int t = threadIdx.x;
  if (blockIdx.x < 32) rowsum[blockIdx.x * 256 + t] = 0.f;
  const int row  = blockIdx.x * 4 + (t >> 6);
  const int lane = t & 63;
  const float4* rp = (const float4*)(z + (size_t)row * D_DIM);
  float4 v[4];
#pragma unroll
  for (int j = 0; j < 4; ++j) v[j] = rp[lane + 64 * j];
  float ss = 0.f;
#pragma unroll
  for (int j = 0; j < 4; ++j)
    ss += v[j].x * v[j].x + v[j].y * v[j].y + v[j].z * v[j].z + v[j].w * v[j].w;
  ss += __shfl_xor(ss, 1);
  ss += __shfl_xor(ss, 2);
  ss += __shfl_xor(ss, 4);
  ss += __shfl_xor(ss, 8);
  ss += __shfl_xor(ss, 16);
  ss += __shfl_xor(ss, 32);
  const float rn = rsqrtf(ss);
  bf16x4_s* op = (bf16x4_s*)(out + (size_t)row * D_DIM);
#pragma unroll
  for (int j = 0; j < 4; ++j) {
    bf16x4_s o;
    o.x = __float2bfloat16(v[j].x * rn);
    o.y = __float2bfloat16(v[j].y * rn);
    o.z = __float2bfloat16(v[j].z * rn);
    o.w = __float2bfloat16(v[j].w * rn);
    op[lane + 64 * j] = o;
  }
}

// ---------------------------------------------------------------------------
// Kernel 2: 256x256-tile NT-GEMM (m = A.B^T) + exp + row-sum + diag capture.
// 8-phase schedule (m201-style): BK=64, 2 LDS slots (A[2][256][32] k-half
// blocks + same for B, 128 KiB). K-tile = 4 phases {(k0,mlo),(k0,mhi),
// (k1,mlo),(k1,mhi)}; each phase: 4-8 ds_read_b128 + stage 1 half-tile of a
// future K-tile + setprio 16xMFMA + barrier. vmcnt(8) at even-phase ends
// (counted, never 0 in steady state); death-driven stage targets (a k-half's
// region is restaged >=1 phase after its last read, barrier-ordered).
// Chunk swizzle c'=c^((row>>1)&3) at 16B granularity (verified 0 conflicts).
// ---------------------------------------------------------------------------
__global__ void __launch_bounds__(512, 2) simexp_gemm(
    const bf16_t* __restrict__ A, const bf16_t* __restrict__ B,
    float* __restrict__ rowsum, float* __restrict__ pos_sim) {
  constexpr int SLOT = 32768;          // elems per slot: A 16384 + B 16384
  __shared__ bf16_t lds[2 * SLOT];     // 128 KiB

  const int t    = threadIdx.x;
  const int w    = t >> 6;             // 0..7
  const int lane = t & 63;
  const int wr   = w >> 2;             // 0..1 -> rows wr*128..+128
  const int wc   = w & 3;              // 0..3 -> cols wc*64..+64
  const int rb   = blockIdx.y, cb = blockIdx.x;
  const int row0 = rb * 256, col0 = cb * 256;

  // staging map: instr covers elems j*4096 + t*8 within a k-half block
  // [128*(j) + (t>>2)][ (t&3)*8 ]; source chunk pre-swizzled (rule 21).
  const int srow = t >> 2;                             // 0..127
  const int scol = ((t & 3) ^ ((t >> 3) & 3)) * 8;     // swizzled 16B chunk
  const int ldst = w * 512;                            // wave dest base/instr

#define STGA(s, kh, Tt)                                                       \
  do {                                                                        \
    const int gc = (Tt) * 64 + (kh) * 32 + scol;                              \
    GLOAD_LDS16(A + (size_t)(row0 + srow) * D_DIM + gc,                       \
                lds + (s) * SLOT + (kh) * 8192 + ldst);                       \
    GLOAD_LDS16(A + (size_t)(row0 + 128 + srow) * D_DIM + gc,                 \
                lds + (s) * SLOT + (kh) * 8192 + 4096 + ldst);                \
  } while (0)
#define STGB(s, kh, Tt)                                                       \
  do {                                                                        \
    const int gc = (Tt) * 64 + (kh) * 32 + scol;                              \
    GLOAD_LDS16(B + (size_t)(col0 + srow) * D_DIM + gc,                       \
                lds + (s) * SLOT + 16384 + (kh) * 8192 + ldst);               \
    GLOAD_LDS16(B + (size_t)(col0 + 128 + srow) * D_DIM + gc,                 \
                lds + (s) * SLOT + 16384 + (kh) * 8192 + 4096 + ldst);        \
  } while (0)

  // fragment read offsets within a [256][32] k-half block (swizzled)
  int offA[8], offB[4];
#pragma unroll
  for (int m = 0; m < 8; ++m) {
    const int r = wr * 128 + m * 16 + (lane & 15);
    offA[m] = r * 32 + (((lane >> 4) ^ ((r >> 1) & 3)) * 8);
  }
#pragma unroll
  for (int n = 0; n < 4; ++n) {
    const int r = wc * 64 + n * 16 + (lane & 15);
    offB[n] = r * 32 + (((lane >> 4) ^ ((r >> 1) & 3)) * 8);
  }

  f32x4 acc[8][4];
#pragma unroll
  for (int m = 0; m < 8; ++m)
#pragma unroll
    for (int n = 0; n < 4; ++n) acc[m][n] = (f32x4){0.f, 0.f, 0.f, 0.f};

#define LOADB4_(s, kh)                                                        \
  do {                                                                        \
    _Pragma("unroll") for (int n = 0; n < 4; ++n) bfv[n] =                    \
        *(const s16x8*)&lds[(s) * SLOT + 16384 + (kh) * 8192 + offB[n]];      \
  } while (0)
#define LOADA4_(s, kh, mb)                                                    \
  do {                                                                        \
    _Pragma("unroll") for (int m = 0; m < 4; ++m) afv[m] =                    \
        *(const s16x8*)&lds[(s) * SLOT + (kh) * 8192 + offA[(mb) + m]];       \
  } while (0)
#define MFMA16_(mb)                                                           \
  do {                                                                        \
    __builtin_amdgcn_s_setprio(1);                                            \
    _Pragma("unroll") for (int m = 0; m < 4; ++m)                             \
        _Pragma("unroll") for (int n = 0; n < 4; ++n) acc[(mb) + m][n] =      \
            __builtin_amdgcn_mfma_f32_16x16x32_bf16(afv[m], bfv[n],           \
                                                    acc[(mb) + m][n], 0, 0, 0); \
    __builtin_amdgcn_s_setprio(0);                                            \
  } while (0)

// one K-tile window = 4 phases; S1..S4 staged halves, W2/W4 counted waits
#define KWIN(s, S1, S2, S3, S4, W2, W4)                                       \
  do {                                                                        \
    s16x8 bfv[4], afv[4];                                                     \
    LOADB4_(s, 0); LOADA4_(s, 0, 0); S1; MFMA16_(0); BARRIER_();              \
    LOADA4_(s, 0, 4); S2; MFMA16_(4); W2; BARRIER_();                         \
    LOADB4_(s, 1); LOADA4_(s, 1, 0); S3; MFMA16_(0); BARRIER_();              \
    LOADA4_(s, 1, 4); S4; MFMA16_(4); W4; BARRIER_();                         \
  } while (0)

  // prologue: k0(T0), k1(T0), k0(T1) — 6 halves, 12 loads; keep last 4 halves
  STGA(0, 0, 0); STGB(0, 0, 0);
  STGA(0, 1, 0); STGB(0, 1, 0);
  STGA(1, 0, 1); STGB(1, 0, 1);
  WAITCNT_VM(8);
  BARRIER_();

#pragma unroll 1
  for (int i = 0; i < 7; ++i) {
    const int T = 2 * i;
    KWIN(0, STGA(1, 1, T + 1), STGB(1, 1, T + 1),
            STGA(0, 0, T + 2), STGB(0, 0, T + 2),
            WAITCNT_VM(8), WAITCNT_VM(8));
    KWIN(1, STGA(0, 1, T + 2), STGB(0, 1, T + 2),
            STGA(1, 0, T + 3), STGB(1, 0, T + 3),
            WAITCNT_VM(8), WAITCNT_VM(8));
  }
  // tail: T=14,15 — stages for T+2/T+3 skipped; waits drain 8 -> 4 -> 0
  KWIN(0, STGA(1, 1, 15), STGB(1, 1, 15), , , WAITCNT_VM(8), WAITCNT_VM(4));
  KWIN(1, , , , , WAITCNT_VM(0), );

  // ---- epilogue ----
  if (rb == cb) {
#pragma unroll
    for (int m = 0; m < 8; ++m)
#pragma unroll
      for (int n = 0; n < 4; ++n)
#pragma unroll
        for (int r = 0; r < 4; ++r) {
          const int grow = wr * 128 + m * 16 + (lane >> 4) * 4 + r;
          const int gcol = wc * 64 + n * 16 + (lane & 15);
          if (grow == gcol) pos_sim[row0 + grow] = acc[m][n][r];
        }
  }

  __syncthreads();                       // all phase reads done; reuse lds
  float* red = (float*)lds;              // [4 wc][256 rows]
#pragma unroll
  for (int m = 0; m < 8; ++m)
#pragma unroll
    for (int r = 0; r < 4; ++r) {
      float s = 0.f;
#pragma unroll
      for (int n = 0; n < 4; ++n) s += __expf(acc[m][n][r]);
      s += __shfl_xor(s, 1);
      s += __shfl_xor(s, 2);
      s += __shfl_xor(s, 4);
      s += __shfl_xor(s, 8);
      if ((lane & 15) == 0) {
        const int row_local = wr * 128 + m * 16 + (lane >> 4) * 4 + r;
        red[wc * 256 + row_local] = s;
      }
    }
  __syncthreads();
  if (t < 256) {
    const float s4 = red[t] + red[256 + t] + red[512 + t] + red[768 + t];
    atomicAdd(&rowsum[row0 + t], s4);
  }
#undef STGA
#undef STGB
#undef LOADB4_
#undef LOADA4_
#undef MFMA16_
#undef KWIN
}

// ---------------------------------------------------------------------------
// Kernel 3: finalize — p_ij, loss, means. Single block.
// ---------------------------------------------------------------------------
__global__ void __launch_bounds__(256) finalize_kernel(
    const float* __restrict__ rowsum, const float* __restrict__ pos_sim,
    float* __restrict__ out) {
  const int t = threadIdx.x;
  double lsum = 0.0, psum = 0.0;
  for (int i = t; i < N_ROWS; i += 256) {
    const float ps    = pos_sim[i];
    const float pos   = expf(ps);
    const float denom = rowsum[i] - pos;
    const float p     = pos / denom;
    lsum += (double)(-logf(p) - p * ps);
    psum += (double)p;
  }
  for (int off = 32; off; off >>= 1) {
    lsum += __shfl_down(lsum, off);
    psum += __shfl_down(psum, off);
  }
  __shared__ double sl[4], sp[4];
  const int wv = t >> 6, ln = t & 63;
  if (ln == 0) { sl[wv] = lsum; sp[wv] = psum; }
  __syncthreads();
  if (t == 0) {
    const double L = sl[0] + sl[1] + sl[2] + sl[3];
    const double P = sp[0] + sp[1] + sp[2] + sp[3];
    out[0] = (float)(L / N_ROWS);
    out[1] = (float)(P / N_ROWS);
  }
}

// ---------------------------------------------------------------------------
extern "C" void kernel_launch(void* const* d_in, const int* in_sizes, int n_in,
                              void* d_out, int out_size, void* d_ws,
                              size_t ws_size, hipStream_t stream) {
  const float* z = (const float*)d_in[0];
  float* out = (float*)d_out;

  char* ws = (char*)d_ws;
  bf16_t* AB = (bf16_t*)ws;  // normalized bf16, 2*N*D = 32 MiB
  float* rowsum  = (float*)(ws + (size_t)2 * N_ROWS * D_DIM * sizeof(bf16_t));
  float* pos_sim = rowsum + N_ROWS;

  normalize_kernel<<<2 * N_ROWS / 4, 256, 0, stream>>>(z, AB, rowsum);

  bf16_t* Amat = AB;
  bf16_t* Bmat = AB + (size_t)N_ROWS * D_DIM;
  dim3 grid(N_ROWS / 256, N_ROWS / 256);  // (cb, rb) = 32 x 32
  simexp_gemm<<<grid, 512, 0, stream>>>(Amat, Bmat, rowsum, pos_sim);

  finalize_kernel<<<1, 256, 0, stream>>>(rowsum, pos_sim, out);
}

// Round 11
// 220.123 us; speedup vs baseline: 1.1194x; 1.0448x over previous
//
#include <hip/hip_runtime.h>
#include <hip/hip_bf16.h>
#include <hip/hip_fp8.h>

typedef __attribute__((ext_vector_type(4))) float f32x4;
typedef unsigned char u8;

#define N_ROWS 8192
#define D_DIM  1024

// async global->LDS, 16B/lane; LDS dest = wave-uniform base + lane*16B
#define GLOAD_LDS16(g, l)                                                     \
  __builtin_amdgcn_global_load_lds(                                           \
      (const __attribute__((address_space(1))) void*)(g),                     \
      (__attribute__((address_space(3))) void*)(l), 16, 0, 0)

#define WAITCNT_VM(n) asm volatile("s_waitcnt vmcnt(" #n ")" ::: "memory")
#define BARRIER_()                                                            \
  do {                                                                        \
    asm volatile("" ::: "memory");                                            \
    __builtin_amdgcn_s_barrier();                                             \
    asm volatile("" ::: "memory");                                            \
  } while (0)

// ---------------------------------------------------------------------------
// Kernel 1: per-row L2 normalize (fp32 in) -> fp8 e4m3 out. One WAVE per row
// (64 lanes x 16 elems). Blocks 0..31 also zero the rowsum accumulator.
// ---------------------------------------------------------------------------
__global__ void __launch_bounds__(256) normq_kernel(
    const float* __restrict__ z, u8* __restrict__ out,
    float* __restrict__ rowsum) {
  const int t = threadIdx.x;
  if (blockIdx.x < 32) rowsum[blockIdx.x * 256 + t] = 0.f;
  const int row  = blockIdx.x * 4 + (t >> 6);
  const int lane = t & 63;
  const float4* rp = (const float4*)(z + (size_t)row * D_DIM) + lane * 4;
  float4 v[4];
#pragma unroll
  for (int j = 0; j < 4; ++j) v[j] = rp[j];
  float ss = 0.f;
#pragma unroll
  for (int j = 0; j < 4; ++j)
    ss += v[j].x * v[j].x + v[j].y * v[j].y + v[j].z * v[j].z + v[j].w * v[j].w;
  ss += __shfl_xor(ss, 1);
  ss += __shfl_xor(ss, 2);
  ss += __shfl_xor(ss, 4);
  ss += __shfl_xor(ss, 8);
  ss += __shfl_xor(ss, 16);
  ss += __shfl_xor(ss, 32);
  const float rn = rsqrtf(ss);
  uint wds[4];
#pragma unroll
  for (int j = 0; j < 4; ++j) {
    __hip_fp8_e4m3 q0(v[j].x * rn), q1(v[j].y * rn);
    __hip_fp8_e4m3 q2(v[j].z * rn), q3(v[j].w * rn);
    wds[j] = (uint)q0.__x | ((uint)q1.__x << 8) | ((uint)q2.__x << 16) |
             ((uint)q3.__x << 24);
  }
  uint4 o; o.x = wds[0]; o.y = wds[1]; o.z = wds[2]; o.w = wds[3];
  *(uint4*)(out + (size_t)row * D_DIM + lane * 16) = o;
}

// ---------------------------------------------------------------------------
// Kernel 2: 256x256-tile NT-GEMM in fp8 e4m3 (m = A.B^T, A,B normalized fp8
// row-major) + exp + row-sum + diag capture. 512 threads = 8 waves (2x4);
// wave output 128x64. K-tile = 128 (4 k-quarters of 32), 2 LDS slots of
// {A 4x8KB quarters + B 4x8KB} = 128 KiB. Per quarter-pair: vmcnt(6) +
// barrier, 12x ds_read_b64, 2 staged gloads (A,B quarter of next tile),
// 2x16 MFMA (mfma_f32_16x16x32_fp8_fp8, setprio-wrapped). Counted vmcnt
// never 0 until tail (6,4,2,0). Swizzle: 16B-half h ^= (row>>2)&1 applied
// pre-swizzled on the global source + on ds_read addrs (involution);
// residual 2-way bank alias is free (m136).
// ---------------------------------------------------------------------------
__global__ void __launch_bounds__(512, 2) simexp_gemm(
    const u8* __restrict__ A, const u8* __restrict__ B,
    float* __restrict__ rowsum, float* __restrict__ pos_sim) {
  __shared__ u8 lds[131072];          // 2 slots x (A 32KB + B 32KB)

  const int t    = threadIdx.x;
  const int w    = t >> 6;            // 0..7
  const int lane = t & 63;
  const int wr   = w >> 2;            // 0..1 -> rows wr*128..+128
  const int wc   = w & 3;             // 0..3 -> cols wc*64..+64
  const int rb   = blockIdx.y, cb = blockIdx.x;
  const int row0 = rb * 256, col0 = cb * 256;

  // staging: thread t covers quarter row t>>1, 16B-half t&1 (8KB per quarter)
  const int srow  = t >> 1;                              // 0..255
  const int scolq = ((t & 1) ^ ((srow >> 2) & 1)) * 16;  // swizzled src half
  const int ldst  = w * 1024;                            // wave slice in qtr

#define STGA(ss, q, T)                                                        \
  GLOAD_LDS16(A + (size_t)(row0 + srow) * D_DIM + (T) * 128 + (q) * 32 + scolq,\
              lds + (ss) * 65536 + (q) * 8192 + ldst)
#define STGB(ss, q, T)                                                        \
  GLOAD_LDS16(B + (size_t)(col0 + srow) * D_DIM + (T) * 128 + (q) * 32 + scolq,\
              lds + (ss) * 65536 + 32768 + (q) * 8192 + ldst)

  // fragment read byte-offsets within a [256][32] fp8 quarter (swizzled)
  const int c8 = lane >> 4;           // 8B k-chunk 0..3
  int offA[8], offB[4];
#pragma unroll
  for (int m = 0; m < 8; ++m) {
    const int r = wr * 128 + m * 16 + (lane & 15);
    offA[m] = r * 32 + ((c8 ^ (((r >> 2) & 1) << 1)) * 8);
  }
#pragma unroll
  for (int n = 0; n < 4; ++n) {
    const int r = wc * 64 + n * 16 + (lane & 15);
    offB[n] = r * 32 + ((c8 ^ (((r >> 2) & 1) << 1)) * 8);
  }

  f32x4 acc[8][4];
#pragma unroll
  for (int m = 0; m < 8; ++m)
#pragma unroll
    for (int n = 0; n < 4; ++n) acc[m][n] = (f32x4){0.f, 0.f, 0.f, 0.f};

// one k-quarter = 2 phases {B+A(lo) reads, SA, 16 MFMA} {A(hi) reads, SB, 16 MFMA}
#define KQ2(ss, q, WN, SA, SB)                                                \
  do {                                                                        \
    WAITCNT_VM(WN);                                                           \
    BARRIER_();                                                               \
    long bfv[4], afv[4];                                                      \
    _Pragma("unroll") for (int n = 0; n < 4; ++n) bfv[n] =                    \
        *(const long*)(lds + (ss) * 65536 + 32768 + (q) * 8192 + offB[n]);    \
    _Pragma("unroll") for (int m = 0; m < 4; ++m) afv[m] =                    \
        *(const long*)(lds + (ss) * 65536 + (q) * 8192 + offA[m]);            \
    SA;                                                                       \
    __builtin_amdgcn_s_setprio(1);                                            \
    _Pragma("unroll") for (int m = 0; m < 4; ++m)                             \
        _Pragma("unroll") for (int n = 0; n < 4; ++n) acc[m][n] =             \
            __builtin_amdgcn_mfma_f32_16x16x32_fp8_fp8(afv[m], bfv[n],        \
                                                       acc[m][n], 0, 0, 0);   \
    __builtin_amdgcn_s_setprio(0);                                            \
    _Pragma("unroll") for (int m = 0; m < 4; ++m) afv[m] =                    \
        *(const long*)(lds + (ss) * 65536 + (q) * 8192 + offA[4 + m]);        \
    SB;                                                                       \
    __builtin_amdgcn_s_setprio(1);                                            \
    _Pragma("unroll") for (int m = 0; m < 4; ++m)                             \
        _Pragma("unroll") for (int n = 0; n < 4; ++n) acc[4 + m][n] =         \
            __builtin_amdgcn_mfma_f32_16x16x32_fp8_fp8(afv[m], bfv[n],        \
                                                       acc[4 + m][n], 0, 0, 0);\
    __builtin_amdgcn_s_setprio(0);                                            \
  } while (0)

  // prologue: stage all 4 quarters of tile 0 (A-q,B-q interleaved = drain order)
#pragma unroll
  for (int q = 0; q < 4; ++q) { STGA(0, q, 0); STGB(0, q, 0); }

#pragma unroll 1
  for (int T = 0; T < 7; ++T) {
    const int ss = T & 1, ns = ss ^ 1;
    KQ2(ss, 0, 6, STGA(ns, 0, T + 1), STGB(ns, 0, T + 1));
    KQ2(ss, 1, 6, STGA(ns, 1, T + 1), STGB(ns, 1, T + 1));
    KQ2(ss, 2, 6, STGA(ns, 2, T + 1), STGB(ns, 2, T + 1));
    KQ2(ss, 3, 6, STGA(ns, 3, T + 1), STGB(ns, 3, T + 1));
  }
  // tail: tile 7 in slot 1; no stages; drain 6 -> 4 -> 2 -> 0
  KQ2(1, 0, 6, , );
  KQ2(1, 1, 4, , );
  KQ2(1, 2, 2, , );
  KQ2(1, 3, 0, , );

  // ---- epilogue ----
  if (rb == cb) {
#pragma unroll
    for (int m = 0; m < 8; ++m)
#pragma unroll
      for (int n = 0; n < 4; ++n)
#pragma unroll
        for (int r = 0; r < 4; ++r) {
          const int grow = wr * 128 + m * 16 + (lane >> 4) * 4 + r;
          const int gcol = wc * 64 + n * 16 + (lane & 15);
          if (grow == gcol) pos_sim[row0 + grow] = acc[m][n][r];
        }
  }

  __syncthreads();                       // all phase reads done; reuse lds
  float* red = (float*)lds;              // [4 wc][256 rows]
#pragma unroll
  for (int m = 0; m < 8; ++m)
#pragma unroll
    for (int r = 0; r < 4; ++r) {
      float s = 0.f;
#pragma unroll
      for (int n = 0; n < 4; ++n) s += __expf(acc[m][n][r]);
      s += __shfl_xor(s, 1);
      s += __shfl_xor(s, 2);
      s += __shfl_xor(s, 4);
      s += __shfl_xor(s, 8);
      if ((lane & 15) == 0) {
        const int row_local = wr * 128 + m * 16 + (lane >> 4) * 4 + r;
        red[wc * 256 + row_local] = s;
      }
    }
  __syncthreads();
  if (t < 256) {
    const float s4 = red[t] + red[256 + t] + red[512 + t] + red[768 + t];
    atomicAdd(&rowsum[row0 + t], s4);
  }
#undef STGA
#undef STGB
#undef KQ2
}

// ---------------------------------------------------------------------------
// Kernel 3: finalize — p_ij, loss, means. Single block.
// ---------------------------------------------------------------------------
__global__ void __launch_bounds__(256) finalize_kernel(
    const float* __restrict__ rowsum, const float* __restrict__ pos_sim,
    float* __restrict__ out) {
  const int t = threadIdx.x;
  double lsum = 0.0, psum = 0.0;
  for (int i = t; i < N_ROWS; i += 256) {
    const float ps    = pos_sim[i];
    const float pos   = expf(ps);
    const float denom = rowsum[i] - pos;
    const float p     = pos / denom;
    lsum += (double)(-logf(p) - p * ps);
    psum += (double)p;
  }
  for (int off = 32; off; off >>= 1) {
    lsum += __shfl_down(lsum, off);
    psum += __shfl_down(psum, off);
  }
  __shared__ double sl[4], sp[4];
  const int wv = t >> 6, ln = t & 63;
  if (ln == 0) { sl[wv] = lsum; sp[wv] = psum; }
  __syncthreads();
  if (t == 0) {
    const double L = sl[0] + sl[1] + sl[2] + sl[3];
    const double P = sp[0] + sp[1] + sp[2] + sp[3];
    out[0] = (float)(L / N_ROWS);
    out[1] = (float)(P / N_ROWS);
  }
}

// ---------------------------------------------------------------------------
extern "C" void kernel_launch(void* const* d_in, const int* in_sizes, int n_in,
                              void* d_out, int out_size, void* d_ws,
                              size_t ws_size, hipStream_t stream) {
  const float* z = (const float*)d_in[0];
  float* out = (float*)d_out;

  char* ws = (char*)d_ws;
  u8* AB = (u8*)ws;  // normalized fp8 e4m3, 2*N*D = 16 MiB
  float* rowsum  = (float*)(ws + (size_t)2 * N_ROWS * D_DIM);
  float* pos_sim = rowsum + N_ROWS;

  normq_kernel<<<2 * N_ROWS / 4, 256, 0, stream>>>(z, AB, rowsum);

  u8* Amat = AB;
  u8* Bmat = AB + (size_t)N_ROWS * D_DIM;
  dim3 grid(N_ROWS / 256, N_ROWS / 256);  // (cb, rb) = 32 x 32
  simexp_gemm<<<grid, 512, 0, stream>>>(Amat, Bmat, rowsum, pos_sim);

  finalize_kernel<<<1, 256, 0, stream>>>(rowsum, pos_sim, out);
}